// Round 6
// baseline (879.908 us; speedup 1.0000x reference)
//
#include <hip/hip_runtime.h>
#include <cstdint>
#include <cstddef>

#define FEATURE_IN 4096
#define FEATURE_OUT 4096
#define RNK 16

typedef __bf16 bf16x8_t __attribute__((ext_vector_type(8)));
typedef __bf16 bf16x4_t __attribute__((ext_vector_type(4)));
typedef float f32x4_t __attribute__((ext_vector_type(4)));

typedef const __attribute__((address_space(1))) f32x4_t* gf4p;
typedef const __attribute__((address_space(1))) bf16x8_t* gb8p;

// ===================== prep1: tiny transposes + x->bf16 convert =====================
// bid 0..15   : labT[16][4096] = bf16(la^T)          (la is [4096][16] fp32)
// bid 16..31  : be[4096][32]   = [bf16(lb^T) | 0]    (lb is [16][4096] fp32)
// bid 32..2079: xb = bf16(x), grid-stride fully-coalesced float4 loads
__global__ __launch_bounds__(256) void prep1(const float* __restrict__ x,
                                             uint16_t* __restrict__ xb,
                                             const float* __restrict__ la,
                                             const float* __restrict__ lb,
                                             uint16_t* __restrict__ labT,
                                             uint16_t* __restrict__ be) {
    const int tid = threadIdx.x;
    const int bid = blockIdx.x;

    if (bid < 16) {
        const int r = tid >> 4, kt = tid & 15;
        const int k0 = bid * 256 + kt * 16;
        bf16x8_t o0, o1;
#pragma unroll
        for (int i = 0; i < 8; ++i) o0[i] = (__bf16)la[(size_t)(k0 + i) * RNK + r];
#pragma unroll
        for (int i = 0; i < 8; ++i) o1[i] = (__bf16)la[(size_t)(k0 + 8 + i) * RNK + r];
        *(bf16x8_t*)(labT + (size_t)r * FEATURE_IN + k0) = o0;
        *(bf16x8_t*)(labT + (size_t)r * FEATURE_IN + k0 + 8) = o1;
        return;
    }
    if (bid < 32) {
        const int n = (bid - 16) * 256 + tid;
        bf16x8_t o0, o1, zz;
#pragma unroll
        for (int i = 0; i < 8; ++i) o0[i] = (__bf16)lb[(size_t)i * FEATURE_OUT + n];
#pragma unroll
        for (int i = 0; i < 8; ++i) o1[i] = (__bf16)lb[(size_t)(8 + i) * FEATURE_OUT + n];
#pragma unroll
        for (int i = 0; i < 8; ++i) zz[i] = (__bf16)0.f;
        *(bf16x8_t*)(be + (size_t)n * 32) = o0;
        *(bf16x8_t*)(be + (size_t)n * 32 + 8) = o1;
        *(bf16x8_t*)(be + (size_t)n * 32 + 16) = zz;
        *(bf16x8_t*)(be + (size_t)n * 32 + 24) = zz;
        return;
    }
    const int tg = (bid - 32) * 256 + tid;
    const f32x4_t* xp = (const f32x4_t*)x;
    bf16x4_t* op = (bf16x4_t*)xb;
#pragma unroll
    for (int i = 0; i < 16; ++i) {
        const int idx = i * 524288 + tg;
        f32x4_t v = xp[idx];
        bf16x4_t o;
        o[0] = (__bf16)v[0]; o[1] = (__bf16)v[1]; o[2] = (__bf16)v[2]; o[3] = (__bf16)v[3];
        op[idx] = o;
    }
}

// ===================== xa_gemm: xe[8192][32] = [bf16(2 * Xb x la) | 0] ==============
// 64 blocks x 256 thr (4 waves); block = 128 m-rows, full K.  A staged via gll
// (2 x 8KB dbuf, same slot-permutation as main gemm); B-frag (labT) loaded straight
// from LLC; mfma 16x16x32, n-dim = r (16 wide).
#define XGLL(SRC, DSTOFF)                                                                \
    __builtin_amdgcn_global_load_lds(                                                    \
        (const __attribute__((address_space(1))) void*)(SRC),                            \
        (__attribute__((address_space(3))) void*)(lds + (DSTOFF) + wv2 * 1024), 16, 0, 0)

__global__ __launch_bounds__(256) void xa_gemm(const uint16_t* __restrict__ xbu,
                                               const uint16_t* __restrict__ labTu,
                                               uint16_t* __restrict__ xe) {
    __shared__ __align__(16) char lds[16384];
    const __bf16* Xb = (const __bf16*)xbu;
    const __bf16* Lt = (const __bf16*)labTu;

    const int tid = threadIdx.x;
    const int wv2 = tid >> 6;
    const int lane = tid & 63;
    const int l15 = lane & 15;
    const int q = lane >> 4;
    const int m0 = blockIdx.x * 128;

    const int srow = tid >> 2;
    const int sq = ((tid & 3) - (srow >> 1)) & 3;
    const __bf16* pX0 = Xb + (size_t)(m0 + srow) * FEATURE_IN + sq * 8;
    const __bf16* pX1 = pX0 + (size_t)64 * FEATURE_IN;

    int aoff2[2];
#pragma unroll
    for (int mi = 0; mi < 2; ++mi) {
        int row = wv2 * 32 + mi * 16 + l15;
        aoff2[mi] = row * 64 + (((row >> 1) + q) & 3) * 16;
    }

    f32x4_t acc2[2];
    acc2[0] = (f32x4_t)0.f; acc2[1] = (f32x4_t)0.f;
    bf16x8_t b2[2];

    XGLL(pX0, 0); XGLL(pX1, 4096);
    pX0 += 32; pX1 += 32;
    b2[0] = *(gb8p)(Lt + (size_t)l15 * FEATURE_IN + q * 8);

#pragma unroll 2
    for (int t = 0; t < 128; ++t) {
        asm volatile("s_waitcnt vmcnt(0)" ::: "memory");
        __builtin_amdgcn_s_barrier();
        const int cur = t & 1;
        bf16x8_t a0 = *(const bf16x8_t*)(lds + cur * 8192 + aoff2[0]);
        bf16x8_t a1 = *(const bf16x8_t*)(lds + cur * 8192 + aoff2[1]);
        if (t < 127) {
            const int nxt = cur ^ 1;
            XGLL(pX0, nxt * 8192); XGLL(pX1, nxt * 8192 + 4096);
            pX0 += 32; pX1 += 32;
            b2[(t + 1) & 1] = *(gb8p)(Lt + (size_t)l15 * FEATURE_IN + (t + 1) * 32 + q * 8);
        }
        acc2[0] = __builtin_amdgcn_mfma_f32_16x16x32_bf16(a0, b2[cur], acc2[0], 0, 0, 0);
        acc2[1] = __builtin_amdgcn_mfma_f32_16x16x32_bf16(a1, b2[cur], acc2[1], 0, 0, 0);
    }

    __bf16* xeb = (__bf16*)xe;
#pragma unroll
    for (int mi = 0; mi < 2; ++mi)
#pragma unroll
        for (int j = 0; j < 4; ++j) {
            const int row = m0 + wv2 * 32 + mi * 16 + q * 4 + j;
            xeb[(size_t)row * 32 + l15] = (__bf16)(2.f * acc2[mi][j]);
            xeb[(size_t)row * 32 + 16 + l15] = (__bf16)0.f;
        }
}

// ========== GEMM: 256x256, BK=32, 4-buf, reg-pipelined, B from W fp32 ==============
// C[M,N] = Xb[M,K] * bf16(W)[N,K]^T + bias + LoRA-ext-tile.  8 waves (2M x 4N).
// Per body t (1 barrier/tile): VMCNT(0) retires {A-gll(t+1), W-loads(t+1)};
// cvt+ds_write B(t+1) -> buf(t+1); read afy(t); issue A-gll(t+2) + W-loads(t+2);
// MFMA-X; lgkmcnt(0); barrier (publishes buf(t+1)); read R0(t+1); MFMA-Y.
// afx single-set (consumed P0, rewritten P1 - WAR-safe), bqr double-set.
// Tile 128 = LoRA extension: A from xe (gll), B from be (bf16 direct).
#define BM 256
#define BN 256
#define BK 32

#define ABUF(b) ((b) * 32768)
#define BBUF(b) ((b) * 32768 + 16384)

#define MFMA16X(S) do { _Pragma("unroll")                                                \
    for (int _mi = 0; _mi < 4; ++_mi) { _Pragma("unroll")                                \
        for (int _ni = 0; _ni < 4; ++_ni)                                                \
            acc[_mi][_ni] = __builtin_amdgcn_mfma_f32_16x16x32_bf16(                     \
                afx[_mi], bqr[S][_ni], acc[_mi][_ni], 0, 0, 0); } } while (0)

#define MFMA16Y(S) do { _Pragma("unroll")                                                \
    for (int _mi = 0; _mi < 4; ++_mi) { _Pragma("unroll")                                \
        for (int _ni = 0; _ni < 4; ++_ni)                                                \
            acc[4 + _mi][_ni] = __builtin_amdgcn_mfma_f32_16x16x32_bf16(                 \
                afy[_mi], bqr[S][_ni], acc[4 + _mi][_ni], 0, 0, 0); } } while (0)

#define READ_AFY(b) do { _Pragma("unroll")                                               \
    for (int _mi = 0; _mi < 4; ++_mi)                                                    \
        afy[_mi] = *(const bf16x8_t*)(lds + ABUF(b) + aoff[4 + _mi]); } while (0)

#define READ_R0(b, SN) do { _Pragma("unroll")                                            \
    for (int _mi = 0; _mi < 4; ++_mi)                                                    \
        afx[_mi] = *(const bf16x8_t*)(lds + ABUF(b) + aoff[_mi]);                        \
    _Pragma("unroll")                                                                    \
    for (int _ni = 0; _ni < 4; ++_ni)                                                    \
        bqr[SN][_ni] = *(const bf16x8_t*)(lds + BBUF(b) + boff[_ni]); } while (0)

#define GLL(SRC, DSTOFF)                                                                 \
    __builtin_amdgcn_global_load_lds(                                                    \
        (const __attribute__((address_space(1))) void*)(SRC),                            \
        (__attribute__((address_space(3))) void*)(lds + (DSTOFF) + wv * 1024), 16, 0, 0)

#define STAGE_A(b) do { GLL(pA0, ABUF(b)); GLL(pA1, ABUF(b) + 8192);                     \
                        pA0 += BK; pA1 += BK; } while (0)

#define BLD_W() do {                                                                     \
    wba0 = *(gf4p)(pW0);     wba1 = *(gf4p)(pW0 + 4);                                    \
    wbb0 = *(gf4p)(pW1);     wbb1 = *(gf4p)(pW1 + 4);                                    \
    pW0 += BK; pW1 += BK; } while (0)

#define BWR_W(BUFI) do {                                                                 \
    bf16x8_t _o0, _o1;                                                                   \
    _o0[0] = (__bf16)wba0[0]; _o0[1] = (__bf16)wba0[1];                                  \
    _o0[2] = (__bf16)wba0[2]; _o0[3] = (__bf16)wba0[3];                                  \
    _o0[4] = (__bf16)wba1[0]; _o0[5] = (__bf16)wba1[1];                                  \
    _o0[6] = (__bf16)wba1[2]; _o0[7] = (__bf16)wba1[3];                                  \
    _o1[0] = (__bf16)wbb0[0]; _o1[1] = (__bf16)wbb0[1];                                  \
    _o1[2] = (__bf16)wbb0[2]; _o1[3] = (__bf16)wbb0[3];                                  \
    _o1[4] = (__bf16)wbb1[0]; _o1[5] = (__bf16)wbb1[1];                                  \
    _o1[6] = (__bf16)wbb1[2]; _o1[7] = (__bf16)wbb1[3];                                  \
    *(bf16x8_t*)(lds + BBUF(BUFI) + bwOff) = _o0;                                        \
    *(bf16x8_t*)(lds + BBUF(BUFI) + 8192 + bwOff) = _o1; } while (0)

#define PBAR() __builtin_amdgcn_s_barrier()
#define PRIO1 __builtin_amdgcn_s_setprio(1)
#define PRIO0 __builtin_amdgcn_s_setprio(0)
#define VMCNT0() asm volatile("s_waitcnt vmcnt(0)" ::: "memory")
#define LGKM0() asm volatile("s_waitcnt lgkmcnt(0)" ::: "memory")
#define SCHEDB() __builtin_amdgcn_sched_barrier(0)

#define BODYF(CUR, S, SN)                                                                \
    VMCNT0();                                                                            \
    BWR_W((CUR + 1) & 3);                                                                \
    READ_AFY(CUR);                                                                       \
    STAGE_A((CUR + 2) & 3);                                                              \
    BLD_W();                                                                             \
    SCHEDB();                                                                            \
    PRIO1; MFMA16X(S); PRIO0;                                                            \
    SCHEDB();                                                                            \
    LGKM0();                                                                             \
    PBAR();                                                                              \
    READ_R0((CUR + 1) & 3, SN);                                                          \
    SCHEDB();                                                                            \
    PRIO1; MFMA16Y(S); PRIO0;                                                            \
    SCHEDB();

__global__ __launch_bounds__(512, 2) void gemm256f(const uint16_t* __restrict__ Au,
                                                   const float* __restrict__ W,
                                                   const uint16_t* __restrict__ xeu,
                                                   const uint16_t* __restrict__ beu,
                                                   const float* __restrict__ bias,
                                                   float* __restrict__ C,
                                                   int M, int N, int K) {
    __shared__ __align__(16) char lds[131072];   // 4 bufs x (A 16K | B 16K)

    const __bf16* A = (const __bf16*)Au;
    const __bf16* XE = (const __bf16*)xeu;
    const __bf16* BE = (const __bf16*)beu;

    const int tid  = threadIdx.x;
    const int wv   = tid >> 6;
    const int lane = tid & 63;
    const int waveM = wv >> 2;
    const int waveN = wv & 3;
    const int l15 = lane & 15;
    const int q   = lane >> 4;

    // T1: bijective XCD-chunk swizzle (nwg=512, 512%8==0)
    const int nbx = N / BN;
    const int nwg = nbx * (M / BM);
    const int bidlin = blockIdx.y * nbx + blockIdx.x;
    const int swz = (bidlin & 7) * (nwg >> 3) + (bidlin >> 3);
    const int by = swz / nbx;
    const int bx = swz - by * nbx;
    const int m0 = by * BM;
    const int n0 = bx * BN;

    // staging source mapping (chunk c -> row c>>2, phys slot c&3)
    const int srow = tid >> 2;
    const int sq   = ((tid & 3) - (srow >> 1)) & 3;
    const int bwOff = srow * 64 + (tid & 3) * 16;
    const __bf16* pA0 = A + (size_t)(m0 + srow) * K + sq * 8;
    const __bf16* pA1 = pA0 + (size_t)128 * K;
    const float* pW0 = W + (size_t)(n0 + srow) * K + sq * 8;
    const float* pW1 = pW0 + (size_t)128 * K;
    const __bf16* pAe0 = XE + (size_t)(m0 + srow) * 32 + sq * 8;
    const __bf16* pAe1 = pAe0 + (size_t)128 * 32;
    const __bf16* pBe0 = BE + (size_t)(n0 + srow) * 32 + sq * 8;
    const __bf16* pBe1 = pBe0 + (size_t)128 * 32;

    int aoff[8], boff[4];
#pragma unroll
    for (int mi = 0; mi < 8; ++mi) {
        int row = waveM * 128 + mi * 16 + l15;
        aoff[mi] = row * 64 + (((row >> 1) + q) & 3) * 16;
    }
#pragma unroll
    for (int ni = 0; ni < 4; ++ni) {
        int row = waveN * 64 + ni * 16 + l15;
        boff[ni] = row * 64 + (((row >> 1) + q) & 3) * 16;
    }

    f32x4_t acc[8][4];
#pragma unroll
    for (int mi = 0; mi < 8; ++mi)
#pragma unroll
        for (int ni = 0; ni < 4; ++ni)
            acc[mi][ni] = (f32x4_t)0.f;

    bf16x8_t afx[4], afy[4], bqr[2][4];
    f32x4_t wba0, wba1, wbb0, wbb1;

    // ---- prologue: buf0 = tile0 (A gll + B cvt-write); tile1 loads in flight ----
    STAGE_A(0);
    BLD_W();                 // W(0)
    VMCNT0();
    BWR_W(0);                // B(0) -> buf0
    STAGE_A(1);
    BLD_W();                 // W(1)
    LGKM0();
    PBAR();                  // buf0 published
    READ_R0(0, 0);           // prime afx/bqr[0] with tile 0

    // ---- main: bodies t=0..123 ----
#pragma unroll 1
    for (int i = 0; i < 31; ++i) {
        BODYF(0, 0, 1)
        BODYF(1, 1, 0)
        BODYF(2, 0, 1)
        BODYF(3, 1, 0)
    }
    BODYF(0, 0, 1)           // t=124: stages A(126), B-write(125), W-load(126)
    BODYF(1, 1, 0)           // t=125: stages A(127), B-write(126), W-load(127)

    // ---- t=126: B-write(127) normal; A-ext gll -> buf0 ----
    VMCNT0();
    BWR_W(3);
    READ_AFY(2);
    GLL(pAe0, ABUF(0)); GLL(pAe1, ABUF(0) + 8192);
    SCHEDB();
    PRIO1; MFMA16X(0); PRIO0;
    SCHEDB();
    LGKM0();
    PBAR();
    READ_R0(3, 1);
    SCHEDB();
    PRIO1; MFMA16Y(0); PRIO0;
    SCHEDB();

    // ---- t=127: ext-B (be, bf16 direct) -> buf0 ----
    VMCNT0();                // drain A-ext gll
    {
        bf16x8_t e0 = *(gb8p)(pBe0);
        bf16x8_t e1 = *(gb8p)(pBe1);
        VMCNT0();            // one-time cold wait on be
        *(bf16x8_t*)(lds + BBUF(0) + bwOff) = e0;
        *(bf16x8_t*)(lds + BBUF(0) + 8192 + bwOff) = e1;
    }
    READ_AFY(3);
    SCHEDB();
    PRIO1; MFMA16X(1); PRIO0;
    SCHEDB();
    LGKM0();
    PBAR();
    READ_R0(0, 0);
    SCHEDB();
    PRIO1; MFMA16Y(1); PRIO0;
    SCHEDB();

    // ---- t=128: LoRA ext tile (zeros in cols 16..31 on both sides) ----
    READ_AFY(0);
    SCHEDB();
    PRIO1; MFMA16X(0); MFMA16Y(0); PRIO0;

    // ---- C write: D layout col=lane&15, row=q*4+j ----
#pragma unroll
    for (int ni = 0; ni < 4; ++ni) {
        const int col = n0 + waveN * 64 + ni * 16 + l15;
        const float bv = bias[col];
#pragma unroll
        for (int mi = 0; mi < 8; ++mi) {
            const int row = m0 + waveM * 128 + mi * 16 + q * 4;
            float* op = C + (size_t)row * N + col;
#pragma unroll
            for (int j = 0; j < 4; ++j)
                op[(size_t)j * N] = acc[mi][ni][j] + bv;
        }
    }
}

extern "C" void kernel_launch(void* const* d_in, const int* in_sizes, int n_in,
                              void* d_out, int out_size, void* d_ws, size_t ws_size,
                              hipStream_t stream) {
    const float* x  = (const float*)d_in[0];   // [4,2048,4096]
    const float* w  = (const float*)d_in[1];   // [4096,4096]  (out,in)
    const float* b  = (const float*)d_in[2];   // [4096]
    const float* la = (const float*)d_in[3];   // [4096,16]
    const float* lb = (const float*)d_in[4];   // [16,4096]
    float* out = (float*)d_out;

    const int M = in_sizes[0] / FEATURE_IN;    // 8192
    const int K = FEATURE_IN;
    const int N = FEATURE_OUT;

    // workspace: xb 64 MiB | labT 128KB | be 256KB | xe 512KB  (= 64.9 MiB)
    uint16_t* xb   = (uint16_t*)d_ws;
    uint16_t* labT = xb + (size_t)M * K;
    uint16_t* be   = labT + (size_t)RNK * K;
    uint16_t* xe   = be + (size_t)N * 32;

    // 1) x -> bf16 + tiny transposes (labT, be)
    prep1<<<2080, 256, 0, stream>>>(x, xb, la, lb, labT, be);

    // 2) xe = [bf16(2 * X x A) | 0]
    xa_gemm<<<64, 256, 0, stream>>>(xb, labT, xe);

    // 3) GEMM + bias + LoRA ext tile (B staged from W fp32 in-kernel)
    {
        dim3 grid(N / BN, M / BM);   // (16, 32)
        gemm256f<<<grid, 512, 0, stream>>>(xb, w, xe, be, b, out, M, N, K);
    }
}

// Round 7
// 512.922 us; speedup vs baseline: 1.7155x; 1.7155x over previous
//
#include <hip/hip_runtime.h>
#include <cstdint>
#include <cstddef>

#define FEATURE_IN 4096
#define FEATURE_OUT 4096
#define RNK 16

typedef __bf16 bf16x8_t __attribute__((ext_vector_type(8)));
typedef __bf16 bf16x4_t __attribute__((ext_vector_type(4)));
typedef float f32x4_t __attribute__((ext_vector_type(4)));

// ================= prep_all: one dispatch, two roles (r3/r4 proven version) =========
// blocks [0, NFUSE)          : Wf[n,k] = bf16(W[n,k] + 2*sum_r A[k,r]*B[r,n])
// blocks [NFUSE, NFUSE+NCVTB): x fp32 -> bf16 (grid-stride, coalesced)
#define FW_KB 128
#define FW_NB 32
#define NFUSE 4096            // (K/FW_KB)*(N/FW_NB) = 32*128
#define NCVTB 2048
#define CVT_THREADS (NCVTB * 256)                   // 524288
#define CVT_CHUNKS 16                               // 8388608 float4s total

__global__ __launch_bounds__(256) void prep_all(const float* __restrict__ x,
                                                uint16_t* __restrict__ xb,
                                                const float* __restrict__ w,
                                                const float* __restrict__ la,
                                                const float* __restrict__ lb,
                                                uint16_t* __restrict__ wf) {
    __shared__ float las[FW_KB * RNK];     // [k][r], 8 KB
    __shared__ float lbs[RNK * FW_NB];     // [r][n], 2 KB

    const int tid = threadIdx.x;

    if (blockIdx.x >= NFUSE) {
        // ---- convert role ----
        const int tg = (blockIdx.x - NFUSE) * 256 + tid;
        const f32x4_t* xp = (const f32x4_t*)x;
        bf16x4_t* op = (bf16x4_t*)xb;
#pragma unroll
        for (int i = 0; i < CVT_CHUNKS; ++i) {
            const int idx = i * CVT_THREADS + tg;
            f32x4_t v = xp[idx];
            bf16x4_t o;
            o[0] = (__bf16)v[0]; o[1] = (__bf16)v[1];
            o[2] = (__bf16)v[2]; o[3] = (__bf16)v[3];
            op[idx] = o;
        }
        return;
    }

    // ---- fuse role ----
    const int bid = blockIdx.x;
    const int kb = (bid & 31) * FW_KB;
    const int nb = (bid >> 5) * FW_NB;

    {
        const float4* src = (const float4*)(la + (size_t)kb * RNK);
        float4* dst = (float4*)las;
        dst[tid] = src[tid];
        dst[tid + 256] = src[tid + 256];
    }
#pragma unroll
    for (int f = tid; f < RNK * FW_NB; f += 256) {
        int r = f >> 5;
        int nl = f & 31;
        lbs[r * FW_NB + nl] = lb[(size_t)r * FEATURE_OUT + nb + nl];
    }
    __syncthreads();

    const int nl = tid >> 3;    // 0..31
    const int kq = tid & 7;     // 0..7, each covers 16 k

    f32x4_t bcol[4];
#pragma unroll
    for (int r4 = 0; r4 < 4; ++r4) {
        f32x4_t v;
#pragma unroll
        for (int j = 0; j < 4; ++j) v[j] = lbs[(r4 * 4 + j) * FW_NB + nl];
        bcol[r4] = v;
    }

    const f32x4_t* las4 = (const f32x4_t*)las;   // index k*4 + r4
    const float* wrow = w + (size_t)(nb + nl) * FEATURE_IN + kb + kq * 16;
    uint16_t* wfrow = wf + (size_t)(nb + nl) * FEATURE_IN + kb + kq * 16;

#pragma unroll
    for (int h = 0; h < 2; ++h) {          // two groups of 8 k
        float4 wv0 = ((const float4*)wrow)[h * 2 + 0];
        float4 wv1 = ((const float4*)wrow)[h * 2 + 1];
        float wfv[8] = {wv0.x, wv0.y, wv0.z, wv0.w, wv1.x, wv1.y, wv1.z, wv1.w};
        bf16x8_t o;
#pragma unroll
        for (int j = 0; j < 8; ++j) {
            const int k = kq * 16 + h * 8 + j;
            float s = 0.f;
#pragma unroll
            for (int rr = 0; rr < 4; ++rr) {
                const int r4 = (rr + kq) & 3;
                f32x4_t av = las4[k * 4 + r4];
                f32x4_t bv = bcol[r4];
                s += av[0] * bv[0] + av[1] * bv[1] + av[2] * bv[2] + av[3] * bv[3];
            }
            o[j] = (__bf16)(wfv[j] + 2.f * s);
        }
        ((bf16x8_t*)wfrow)[h] = o;
    }
}

// ====== GEMM: 256x256, BK=32, 4-buffer stage-3-ahead, 1 barrier/tile ==============
// C[M,N] = Xb[M,K] * Wf[N,K]^T + bias.  8 waves (2M x 4N), reg-pipelined frags.
// Per tile t (buf B=t&3, parity S=t&1):
//   READ_AFY(B) [4 ds] || MFMA-X(S) [16]         (afx/bqr read LAST tile)
//   VMCNT(4)   -- retires exactly tile t+1's 4 loads; t+2's stay in flight
//   LGKM0      -- WAR fence: afy reads of buf B complete before any wave passes
//   PBAR       -- publishes buf(t+1)
//   READ_R0(t+1) [8 ds] || STAGE(t+3) [4 gll] || MFMA-Y(S) [16]
// Issue->wait distance for staged loads = 2 full tiles (~2000 cyc, covers HBM).
// WAR ledger: stage into buf b at tile t phase-Y targets tile t+3; buf b's previous
// tenant (t-1) was last read at tile t-1 phase-X, >=1 barrier earlier.  LDS placement
// row*64 + (((row>>1)+q)&3)*16: measured SQ_LDS_BANK_CONFLICT == 0.
#define BM 256
#define BN 256
#define BK 32
#define NT (FEATURE_IN / BK)   // 128 K-tiles

#define ABUF(b) ((b) * 32768)
#define BBUF(b) ((b) * 32768 + 16384)

#define MFMA16X(S) do { _Pragma("unroll")                                                \
    for (int _mi = 0; _mi < 4; ++_mi) { _Pragma("unroll")                                \
        for (int _ni = 0; _ni < 4; ++_ni)                                                \
            acc[_mi][_ni] = __builtin_amdgcn_mfma_f32_16x16x32_bf16(                     \
                afx[_mi], bqr[S][_ni], acc[_mi][_ni], 0, 0, 0); } } while (0)

#define MFMA16Y(S) do { _Pragma("unroll")                                                \
    for (int _mi = 0; _mi < 4; ++_mi) { _Pragma("unroll")                                \
        for (int _ni = 0; _ni < 4; ++_ni)                                                \
            acc[4 + _mi][_ni] = __builtin_amdgcn_mfma_f32_16x16x32_bf16(                 \
                afy[_mi], bqr[S][_ni], acc[4 + _mi][_ni], 0, 0, 0); } } while (0)

#define READ_AFY(b) do { _Pragma("unroll")                                               \
    for (int _mi = 0; _mi < 4; ++_mi)                                                    \
        afy[_mi] = *(const bf16x8_t*)(lds + ABUF(b) + aoff[4 + _mi]); } while (0)

#define READ_R0(b, SN) do { _Pragma("unroll")                                            \
    for (int _mi = 0; _mi < 4; ++_mi)                                                    \
        afx[_mi] = *(const bf16x8_t*)(lds + ABUF(b) + aoff[_mi]);                        \
    _Pragma("unroll")                                                                    \
    for (int _ni = 0; _ni < 4; ++_ni)                                                    \
        bqr[SN][_ni] = *(const bf16x8_t*)(lds + BBUF(b) + boff[_ni]); } while (0)

#define GLL(SRC, DSTOFF)                                                                 \
    __builtin_amdgcn_global_load_lds(                                                    \
        (const __attribute__((address_space(1))) void*)(SRC),                            \
        (__attribute__((address_space(3))) void*)(lds + (DSTOFF) + wv * 1024), 16, 0, 0)

#define STAGE_AB(b) do {                                                                 \
    GLL(pA0, ABUF(b)); GLL(pA1, ABUF(b) + 8192);                                         \
    GLL(pB0, BBUF(b)); GLL(pB1, BBUF(b) + 8192);                                         \
    pA0 += BK; pA1 += BK; pB0 += BK; pB1 += BK; } while (0)

#define PBAR() __builtin_amdgcn_s_barrier()
#define PRIO1 __builtin_amdgcn_s_setprio(1)
#define PRIO0 __builtin_amdgcn_s_setprio(0)
#define VMCNT(n) asm volatile("s_waitcnt vmcnt(" #n ")" ::: "memory")
#define LGKM0() asm volatile("s_waitcnt lgkmcnt(0)" ::: "memory")
#define SCHEDB() __builtin_amdgcn_sched_barrier(0)

// Full body: tile t in buf B, parity S, stages tile t+3 into buf (B+3)&3.
#define BODY(B, S)                                                                       \
    READ_AFY(B);                                                                         \
    SCHEDB();                                                                            \
    PRIO1; MFMA16X(S); PRIO0;                                                            \
    VMCNT(4);                                                                            \
    LGKM0();                                                                             \
    PBAR();                                                                              \
    STAGE_AB((B + 3) & 3);                                                               \
    READ_R0((B + 1) & 3, (S) ^ 1);                                                       \
    SCHEDB();                                                                            \
    PRIO1; MFMA16Y(S); PRIO0;

// Tail body (no staging): NWAIT retires exactly tile t+1's 4 loads.
#define TAILB(B, S, NWAIT)                                                               \
    READ_AFY(B);                                                                         \
    SCHEDB();                                                                            \
    PRIO1; MFMA16X(S); PRIO0;                                                            \
    VMCNT(NWAIT);                                                                        \
    LGKM0();                                                                             \
    PBAR();                                                                              \
    READ_R0((B + 1) & 3, (S) ^ 1);                                                       \
    SCHEDB();                                                                            \
    PRIO1; MFMA16Y(S); PRIO0;

__global__ __launch_bounds__(512, 2) void gemm256(const uint16_t* __restrict__ Au,
                                                  const uint16_t* __restrict__ Bu,
                                                  const float* __restrict__ bias,
                                                  float* __restrict__ C,
                                                  int M, int N, int K) {
    __shared__ __align__(16) char lds[131072];   // 4 bufs x (A 16K | B 16K)

    const __bf16* A = (const __bf16*)Au;
    const __bf16* B = (const __bf16*)Bu;

    const int tid  = threadIdx.x;
    const int wv   = tid >> 6;          // 0..7
    const int lane = tid & 63;
    const int waveM = wv >> 2;          // 0..1
    const int waveN = wv & 3;           // 0..3
    const int l15 = lane & 15;
    const int q   = lane >> 4;          // fragment k-chunk 0..3

    // T1: bijective XCD-chunk swizzle (nwg=512, 512%8==0)
    const int nbx = N / BN;
    const int nwg = nbx * (M / BM);
    const int bidlin = blockIdx.y * nbx + blockIdx.x;
    const int swz = (bidlin & 7) * (nwg >> 3) + (bidlin >> 3);
    const int by = swz / nbx;
    const int bx = swz - by * nbx;
    const int m0 = by * BM;
    const int n0 = bx * BN;

    // staging source mapping (chunk c -> row c>>2, phys slot c&3)
    const int srow = tid >> 2;
    const int sq   = ((tid & 3) - (srow >> 1)) & 3;
    const __bf16* pA0 = A + (size_t)(m0 + srow) * K + sq * 8;
    const __bf16* pA1 = pA0 + (size_t)128 * K;
    const __bf16* pB0 = B + (size_t)(n0 + srow) * K + sq * 8;
    const __bf16* pB1 = pB0 + (size_t)128 * K;

    // per-thread fragment LDS byte offsets (within a 16 KB tile block)
    int aoff[8], boff[4];
#pragma unroll
    for (int mi = 0; mi < 8; ++mi) {
        int row = waveM * 128 + mi * 16 + l15;
        aoff[mi] = row * 64 + (((row >> 1) + q) & 3) * 16;
    }
#pragma unroll
    for (int ni = 0; ni < 4; ++ni) {
        int row = waveN * 64 + ni * 16 + l15;
        boff[ni] = row * 64 + (((row >> 1) + q) & 3) * 16;
    }

    f32x4_t acc[8][4];
#pragma unroll
    for (int mi = 0; mi < 8; ++mi)
#pragma unroll
        for (int ni = 0; ni < 4; ++ni)
            acc[mi][ni] = (f32x4_t)0.f;

    // fragment registers: afx single-set (WAR-safe: consumed X, rewritten post-bar),
    // afy single-set, bqr double-set by tile parity
    bf16x8_t afx[4], afy[4], bqr[2][4];

    // ---- prologue: stage tiles 0,1,2 -> bufs 0,1,2 (12 loads/wave in flight) ----
    STAGE_AB(0);
    STAGE_AB(1);
    STAGE_AB(2);
    VMCNT(8);                 // retire tile 0's 4 loads; tiles 1,2 in flight
    PBAR();                   // publish buf0
    READ_R0(0, 0);            // prime afx / bqr[0] with tile 0

    // ---- main: t = 0..123 (stage tiles 3..126), 31 x 4-body unroll ----
#pragma unroll 1
    for (int i = 0; i < 31; ++i) {
        BODY(0, 0)
        BODY(1, 1)
        BODY(2, 0)
        BODY(3, 1)
    }
    BODY(0, 0)                // t=124: stages tile 127 -> buf3

    // ---- drain: t=125 (buf1,S=1), t=126 (buf2,S=0), t=127 (buf3,S=1) ----
    TAILB(1, 1, 4)            // VMCNT(4): retires tile 126's loads
    TAILB(2, 0, 0)            // VMCNT(0): retires tile 127's loads
    READ_AFY(3);
    SCHEDB();
    PRIO1; MFMA16X(1); PRIO0;
    PRIO1; MFMA16Y(1); PRIO0;

    // ---- C write: D layout col=lane&15, row=q*4+j ----
#pragma unroll
    for (int ni = 0; ni < 4; ++ni) {
        const int col = n0 + waveN * 64 + ni * 16 + l15;
        const float bv = bias[col];
#pragma unroll
        for (int mi = 0; mi < 8; ++mi) {
            const int row = m0 + waveM * 128 + mi * 16 + q * 4;
            float* op = C + (size_t)row * N + col;
#pragma unroll
            for (int j = 0; j < 4; ++j)
                op[(size_t)j * N] = acc[mi][ni][j] + bv;
        }
    }
}

extern "C" void kernel_launch(void* const* d_in, const int* in_sizes, int n_in,
                              void* d_out, int out_size, void* d_ws, size_t ws_size,
                              hipStream_t stream) {
    const float* x  = (const float*)d_in[0];   // [4,2048,4096]
    const float* w  = (const float*)d_in[1];   // [4096,4096]  (out,in)
    const float* b  = (const float*)d_in[2];   // [4096]
    const float* la = (const float*)d_in[3];   // [4096,16]
    const float* lb = (const float*)d_in[4];   // [16,4096]
    float* out = (float*)d_out;

    const int M = in_sizes[0] / FEATURE_IN;    // 8192
    const int K = FEATURE_IN;
    const int N = FEATURE_OUT;

    uint16_t* xb = (uint16_t*)d_ws;                                  // M*K bf16 = 64 MiB
    uint16_t* wf = (uint16_t*)((char*)d_ws + (size_t)M * K * 2);     // N*K bf16 = 32 MiB

    // 1) prep: x->bf16 + LoRA-folded W->bf16 (single dispatch, both roles)
    prep_all<<<NFUSE + NCVTB, 256, 0, stream>>>(x, xb, w, la, lb, wf);

    // 2) GEMM + bias, 256x256, BK=32, 4-buffer, 1-barrier/tile schedule
    {
        dim3 grid(N / BN, M / BM);   // (16, 32)
        gemm256<<<grid, 512, 0, stream>>>(xb, wf, b, out, M, N, K);
    }
}